// Round 1
// baseline (568.029 us; speedup 1.0000x reference)
//
#include <hip/hip_runtime.h>

typedef _Float16 f16;
typedef _Float16 half8 __attribute__((ext_vector_type(8)));
typedef _Float16 half4_t __attribute__((ext_vector_type(4)));
typedef float f32x4 __attribute__((ext_vector_type(4)));

#define T_SEQ 2048
#define B_SZ 2
#define DM 2048
#define NH 16
#define NKV 4
#define DH 128
#define NQKV 2560   // (16+4)*128
#define M_ROWS 4096 // B*T
#define WIN 1024

// ---------------- fp32 -> f16 elementwise ----------------
__global__ void k_cvt(const float* __restrict__ in, f16* __restrict__ out, int n) {
  int i = (blockIdx.x * 256 + threadIdx.x) * 4;
  if (i >= n) return;
  float4 v = *(const float4*)(in + i);
  half4_t o;
  o[0] = (f16)v.x; o[1] = (f16)v.y; o[2] = (f16)v.z; o[3] = (f16)v.w;
  *(half4_t*)(out + i) = o;
}

// ---------------- fp32 (K,N) -> f16 (N,K) transpose-convert ----------------
__global__ __launch_bounds__(256) void k_cvt_t(const float* __restrict__ W,
                                               f16* __restrict__ Wt, int K, int N) {
  __shared__ float tile[32][33];
  int k0 = blockIdx.x * 32, n0 = blockIdx.y * 32;
  int tx = threadIdx.x & 31, ty = threadIdx.x >> 5; // 32 x 8
#pragma unroll
  for (int r = 0; r < 32; r += 8)
    tile[ty + r][tx] = W[(size_t)(k0 + ty + r) * N + n0 + tx];
  __syncthreads();
#pragma unroll
  for (int r = 0; r < 32; r += 8)
    Wt[(size_t)(n0 + ty + r) * K + k0 + tx] = (f16)tile[tx][ty + r];
}

// ---------------- C[M,N] = A[M,K] * Bt[N,K]^T  (f16 in, fp32 out) ----------------
__global__ __launch_bounds__(256) void k_gemm(const f16* __restrict__ A,
                                              const f16* __restrict__ Bt,
                                              float* __restrict__ C,
                                              int M, int N, int K) {
  __shared__ f16 As[128][40];
  __shared__ f16 Bs[128][40];
  int m0 = blockIdx.y * 128, n0 = blockIdx.x * 128;
  int tid = threadIdx.x, lane = tid & 63, w = tid >> 6;
  int wm = (w >> 1) * 64, wn = (w & 1) * 64;
  int fr = lane & 15, fq = lane >> 4;
  f32x4 acc[4][4] = {};
  int r = tid >> 2, c = (tid & 3) * 8;
  const f16* Arow0 = A + (size_t)(m0 + r) * K + c;
  const f16* Arow1 = A + (size_t)(m0 + r + 64) * K + c;
  bool bv0 = (n0 + r) < N, bv1 = (n0 + r + 64) < N;
  const f16* Brow0 = Bt + (size_t)(n0 + r) * K + c;
  const f16* Brow1 = Bt + (size_t)(n0 + r + 64) * K + c;
  half8 z8;
#pragma unroll
  for (int e = 0; e < 8; ++e) z8[e] = (f16)0.0f;
  for (int k0 = 0; k0 < K; k0 += 32) {
    *(half8*)&As[r][c]      = *(const half8*)&Arow0[k0];
    *(half8*)&As[r + 64][c] = *(const half8*)&Arow1[k0];
    *(half8*)&Bs[r][c]      = bv0 ? *(const half8*)&Brow0[k0] : z8;
    *(half8*)&Bs[r + 64][c] = bv1 ? *(const half8*)&Brow1[k0] : z8;
    __syncthreads();
    half8 af[4], bf[4];
#pragma unroll
    for (int i = 0; i < 4; ++i) af[i] = *(const half8*)&As[wm + i * 16 + fr][fq * 8];
#pragma unroll
    for (int j = 0; j < 4; ++j) bf[j] = *(const half8*)&Bs[wn + j * 16 + fr][fq * 8];
#pragma unroll
    for (int i = 0; i < 4; ++i)
#pragma unroll
      for (int j = 0; j < 4; ++j)
        acc[i][j] = __builtin_amdgcn_mfma_f32_16x16x32_f16(af[i], bf[j], acc[i][j], 0, 0, 0);
    __syncthreads();
  }
#pragma unroll
  for (int i = 0; i < 4; ++i) {
    int row = m0 + wm + i * 16 + fq * 4;
#pragma unroll
    for (int j = 0; j < 4; ++j) {
      int col = n0 + wn + j * 16 + fr;
      if (col < N) {
        float* Cp = C + (size_t)row * N + col;
#pragma unroll
        for (int rr = 0; rr < 4; ++rr) Cp[(size_t)rr * N] = acc[i][j][rr];
      }
    }
  }
}

// ---------------- RMSNorm + RoPE + scale + pack q/k/v as f16 ----------------
__global__ __launch_bounds__(256) void k_postproc(
    const float* __restrict__ C1, const float* __restrict__ C2,
    const float* __restrict__ brk, const float* __restrict__ sscal,
    f16* __restrict__ q16, f16* __restrict__ k16, f16* __restrict__ v16) {
  int row = blockIdx.x;              // b*T + t
  int b = row >> 11, t = row & 2047;
  int lane = threadIdx.x & 63, wid = threadIdx.x >> 6;
  int ridx = lane & 31;
  float inv_freq = powf(10000.0f, -(float)(2 * ridx) / 64.0f);
  float fr = (float)t * inv_freq;
  float cs = cosf(fr), sn = sinf(fr);
  float logpos = logf(fminf((float)(t + 1), 1024.0f));
  const float rsqrt_d = 0.08838834764831845f;  // 1/sqrt(128)
#pragma unroll
  for (int p = 0; p < 5; ++p) {
    int h = p * 4 + wid; // 0..19
    float v0 = C1[(size_t)row * NQKV + h * 128 + lane];
    float v1 = C1[(size_t)row * NQKV + h * 128 + 64 + lane];
    float ss = v0 * v0 + v1 * v1;
#pragma unroll
    for (int m = 1; m < 64; m <<= 1) ss += __shfl_xor(ss, m);
    float rms = rsqrtf(ss * (1.0f / 128.0f) + 1e-6f);
    v0 *= rms; v1 *= rms;
    if (h < NH) {
      // q head: v0 = nope dim (lane), v1 = rope dim (lane within [0,64))
      float part = __shfl_xor(v1, 32);
      float vr = (lane < 32) ? (v1 * cs + part * sn) : (v1 * cs - part * sn);
      float scale = sscal[h] * logpos * rsqrt_d;
      size_t qb = ((size_t)(b * NH + h) * T_SEQ + t) * DH;
      q16[qb + lane]      = (f16)(v0 * scale);
      q16[qb + 64 + lane] = (f16)(vr * scale);
    } else {
      int hk = h - NH;
      size_t kb = ((size_t)(b * NKV + hk) * T_SEQ + t) * DH;
      k16[kb + lane]      = (f16)v0;  // tied kv
      v16[kb + lane]      = (f16)v0;  // tied kv
      v16[kb + 64 + lane] = (f16)v1;  // v
    }
  }
  if (wid == 0) {
    float kr = C2[(size_t)row * 64 + lane] + brk[lane];
    float part = __shfl_xor(kr, 32);
    float vr = (lane < 32) ? (kr * cs + part * sn) : (kr * cs - part * sn);
    f16 hv = (f16)vr;
#pragma unroll
    for (int hk = 0; hk < NKV; ++hk)
      k16[((size_t)(b * NKV + hk) * T_SEQ + t) * DH + 64 + lane] = hv;
  }
}

// ---------------- sliding-window flash attention + silu(g) epilogue ----------------
__global__ __launch_bounds__(256) void k_attn(
    const f16* __restrict__ q16, const f16* __restrict__ k16, const f16* __restrict__ v16,
    const float* __restrict__ g, float* __restrict__ out) {
  __shared__ f16 Ks[64][DH + 8];     // 64 x 136
  __shared__ f16 Vs[DH][64 + 8];     // transposed: [d][j]
  __shared__ f16 Ps[4][16][64 + 8];  // per-wave P staging
  int qt = blockIdx.x, h = blockIdx.y, b = blockIdx.z;
  int hk = h >> 2;
  int tid = threadIdx.x, lane = tid & 63, w = tid >> 6;
  int i0 = qt * 64;
  int iw = i0 + w * 16;              // wave's first q row
  int fr = lane & 15, fq = lane >> 4;

  const f16* qbase = q16 + ((size_t)(b * NH + h) * T_SEQ + iw + fr) * DH;
  half8 qf[4];
#pragma unroll
  for (int kb = 0; kb < 4; ++kb) qf[kb] = *(const half8*)&qbase[kb * 32 + fq * 8];

  f32x4 o[8] = {};
  float mrow[4] = {-1e30f, -1e30f, -1e30f, -1e30f};
  float lrow[4] = {0.f, 0.f, 0.f, 0.f};

  int jt0 = (i0 - WIN) > 0 ? (i0 - WIN) / 64 : 0;
  const f16* kg = k16 + (size_t)(b * NKV + hk) * T_SEQ * DH;
  const f16* vg = v16 + (size_t)(b * NKV + hk) * T_SEQ * DH;
  int sr = tid >> 4;           // 0..15
  int sc = (tid & 15) * 8;     // 0..120

  for (int jt = jt0; jt <= qt; ++jt) {
    int j0 = jt * 64;
#pragma unroll
    for (int p = 0; p < 4; ++p) {
      int j = p * 16 + sr;
      *(half8*)&Ks[j][sc] = *(const half8*)&kg[(size_t)(j0 + j) * DH + sc];
      half8 vv = *(const half8*)&vg[(size_t)(j0 + j) * DH + sc];
#pragma unroll
      for (int e = 0; e < 8; ++e) Vs[sc + e][j] = vv[e];
    }
    __syncthreads();
    // S = Q K^T  (16 x 64 per wave)
    f32x4 s[4] = {};
#pragma unroll
    for (int nf = 0; nf < 4; ++nf)
#pragma unroll
      for (int kb = 0; kb < 4; ++kb) {
        half8 bf = *(const half8*)&Ks[nf * 16 + fr][kb * 32 + fq * 8];
        s[nf] = __builtin_amdgcn_mfma_f32_16x16x32_f16(qf[kb], bf, s[nf], 0, 0, 0);
      }
    // mask + online softmax
    float tm[4] = {-1e30f, -1e30f, -1e30f, -1e30f};
#pragma unroll
    for (int nf = 0; nf < 4; ++nf) {
      int jc = j0 + nf * 16 + fr;
#pragma unroll
      for (int r = 0; r < 4; ++r) {
        int ir = iw + fq * 4 + r;
        if (!(jc <= ir && jc >= ir - WIN)) s[nf][r] = -1e30f;
        tm[r] = fmaxf(tm[r], s[nf][r]);
      }
    }
#pragma unroll
    for (int r = 0; r < 4; ++r) {
      tm[r] = fmaxf(tm[r], __shfl_xor(tm[r], 1));
      tm[r] = fmaxf(tm[r], __shfl_xor(tm[r], 2));
      tm[r] = fmaxf(tm[r], __shfl_xor(tm[r], 4));
      tm[r] = fmaxf(tm[r], __shfl_xor(tm[r], 8));
    }
    float scl[4], ls[4];
#pragma unroll
    for (int r = 0; r < 4; ++r) {
      float mn = fmaxf(mrow[r], tm[r]);
      scl[r] = expf(mrow[r] - mn);
      mrow[r] = mn;
      ls[r] = 0.f;
    }
#pragma unroll
    for (int nf = 0; nf < 4; ++nf)
#pragma unroll
      for (int r = 0; r < 4; ++r) {
        float pv = expf(s[nf][r] - mrow[r]);
        s[nf][r] = pv;
        ls[r] += pv;
      }
#pragma unroll
    for (int r = 0; r < 4; ++r) {
      float t2 = ls[r];
      t2 += __shfl_xor(t2, 1); t2 += __shfl_xor(t2, 2);
      t2 += __shfl_xor(t2, 4); t2 += __shfl_xor(t2, 8);
      lrow[r] = lrow[r] * scl[r] + t2;
#pragma unroll
      for (int of = 0; of < 8; ++of) o[of][r] *= scl[r];
    }
    // P -> LDS (D-layout -> A-layout via LDS)
#pragma unroll
    for (int nf = 0; nf < 4; ++nf)
#pragma unroll
      for (int r = 0; r < 4; ++r)
        Ps[w][fq * 4 + r][nf * 16 + fr] = (f16)s[nf][r];
    __syncthreads();
    half8 pf0 = *(const half8*)&Ps[w][fr][fq * 8];
    half8 pf1 = *(const half8*)&Ps[w][fr][32 + fq * 8];
#pragma unroll
    for (int of = 0; of < 8; ++of) {
      half8 v0 = *(const half8*)&Vs[of * 16 + fr][fq * 8];
      half8 v1 = *(const half8*)&Vs[of * 16 + fr][32 + fq * 8];
      o[of] = __builtin_amdgcn_mfma_f32_16x16x32_f16(pf0, v0, o[of], 0, 0, 0);
      o[of] = __builtin_amdgcn_mfma_f32_16x16x32_f16(pf1, v1, o[of], 0, 0, 0);
    }
    __syncthreads();
  }
  // epilogue: normalize + silu(g) multiply, write (B,T,H,D)
  const float* gb = g + ((size_t)(b * T_SEQ) + iw) * DM + h * DH;
  float* ob = out + ((size_t)(b * T_SEQ) + iw) * DM + h * DH;
#pragma unroll
  for (int r = 0; r < 4; ++r) {
    float inv = 1.0f / lrow[r];
    int ir = fq * 4 + r;
#pragma unroll
    for (int of = 0; of < 8; ++of) {
      int d = of * 16 + fr;
      float gv = gb[(size_t)ir * DM + d];
      float sig = gv / (1.0f + expf(-gv));
      ob[(size_t)ir * DM + d] = o[of][r] * inv * sig;
    }
  }
}

extern "C" void kernel_launch(void* const* d_in, const int* in_sizes, int n_in,
                              void* d_out, int out_size, void* d_ws, size_t ws_size,
                              hipStream_t stream) {
  const float* x     = (const float*)d_in[0];
  const float* Wqkv  = (const float*)d_in[1];
  const float* Wrk   = (const float*)d_in[2];
  const float* brk   = (const float*)d_in[3];
  const float* sscal = (const float*)d_in[4];
  const float* Wg    = (const float*)d_in[5];
  float* out = (float*)d_out;
  char* ws = (char*)d_ws;
  size_t off = 0;
  auto alloc = [&](size_t bytes) -> void* {
    void* p = ws + off;
    off += (bytes + 255) & ~(size_t)255;
    return p;
  };
  f16* x16     = (f16*)alloc((size_t)M_ROWS * DM * 2);
  f16* WqkvT   = (f16*)alloc((size_t)NQKV * DM * 2);
  f16* WrkT    = (f16*)alloc((size_t)64 * DM * 2);
  f16* WgT     = (f16*)alloc((size_t)DM * DM * 2);
  float* C1    = (float*)alloc((size_t)M_ROWS * NQKV * 4);
  float* C2    = (float*)alloc((size_t)M_ROWS * 64 * 4);
  float* C3    = (float*)alloc((size_t)M_ROWS * DM * 4);
  f16* q16     = (f16*)alloc((size_t)B_SZ * NH * T_SEQ * DH * 2);
  f16* k16     = (f16*)alloc((size_t)B_SZ * NKV * T_SEQ * DH * 2);
  f16* v16     = (f16*)alloc((size_t)B_SZ * NKV * T_SEQ * DH * 2);

  k_cvt<<<(M_ROWS * DM / 4 + 255) / 256, 256, 0, stream>>>(x, x16, M_ROWS * DM);
  k_cvt_t<<<dim3(DM / 32, NQKV / 32), 256, 0, stream>>>(Wqkv, WqkvT, DM, NQKV);
  k_cvt_t<<<dim3(DM / 32, 64 / 32), 256, 0, stream>>>(Wrk, WrkT, DM, 64);
  k_cvt_t<<<dim3(DM / 32, DM / 32), 256, 0, stream>>>(Wg, WgT, DM, DM);

  k_gemm<<<dim3(NQKV / 128, M_ROWS / 128), 256, 0, stream>>>(x16, WqkvT, C1, M_ROWS, NQKV, DM);
  k_gemm<<<dim3(1, M_ROWS / 128), 256, 0, stream>>>(x16, WrkT, C2, M_ROWS, 64, DM);
  k_gemm<<<dim3(DM / 128, M_ROWS / 128), 256, 0, stream>>>(x16, WgT, C3, M_ROWS, DM, DM);

  k_postproc<<<M_ROWS, 256, 0, stream>>>(C1, C2, brk, sscal, q16, k16, v16);

  k_attn<<<dim3(T_SEQ / 64, NH, B_SZ), 256, 0, stream>>>(q16, k16, v16, C3, out);
}

// Round 2
// 410.502 us; speedup vs baseline: 1.3837x; 1.3837x over previous
//
#include <hip/hip_runtime.h>

typedef _Float16 f16;
typedef _Float16 half8 __attribute__((ext_vector_type(8)));
typedef _Float16 half4_t __attribute__((ext_vector_type(4)));
typedef float f32x4 __attribute__((ext_vector_type(4)));

#define T_SEQ 2048
#define B_SZ 2
#define DM 2048
#define NH 16
#define NKV 4
#define DH 128
#define NQKV 2560   // (16+4)*128
#define M_ROWS 4096 // B*T
#define WIN 1024

typedef __attribute__((address_space(1))) const unsigned int guint;
typedef __attribute__((address_space(3))) unsigned int luint;
__device__ __forceinline__ void gload16(const void* g, void* l) {
  __builtin_amdgcn_global_load_lds((guint*)g, (luint*)l, 16, 0, 0);
}

// ---------------- fp32 -> f16 elementwise ----------------
__global__ void k_cvt(const float* __restrict__ in, f16* __restrict__ out, int n) {
  int i = (blockIdx.x * 256 + threadIdx.x) * 4;
  if (i >= n) return;
  float4 v = *(const float4*)(in + i);
  half4_t o;
  o[0] = (f16)v.x; o[1] = (f16)v.y; o[2] = (f16)v.z; o[3] = (f16)v.w;
  *(half4_t*)(out + i) = o;
}

// ---------------- fp32 (K,N) -> f16 (N,K) transpose-convert ----------------
__global__ __launch_bounds__(256) void k_cvt_t(const float* __restrict__ W,
                                               f16* __restrict__ Wt, int K, int N) {
  __shared__ float tile[32][33];
  int k0 = blockIdx.x * 32, n0 = blockIdx.y * 32;
  int tx = threadIdx.x & 31, ty = threadIdx.x >> 5; // 32 x 8
#pragma unroll
  for (int r = 0; r < 32; r += 8)
    tile[ty + r][tx] = W[(size_t)(k0 + ty + r) * N + n0 + tx];
  __syncthreads();
#pragma unroll
  for (int r = 0; r < 32; r += 8)
    Wt[(size_t)(n0 + ty + r) * K + k0 + tx] = (f16)tile[tx][ty + r];
}

// ---------------- f16 [T][128] -> f16 [128][T] per matrix ----------------
__global__ __launch_bounds__(256) void k_vt(const f16* __restrict__ v, f16* __restrict__ vt) {
  __shared__ f16 tile[32][34];
  int t0 = blockIdx.x * 32, d0 = blockIdx.y * 32, m = blockIdx.z;
  int tx = threadIdx.x & 31, ty = threadIdx.x >> 5;
  const f16* src = v + (size_t)m * T_SEQ * DH;
  f16* dst = vt + (size_t)m * T_SEQ * DH;
#pragma unroll
  for (int r = 0; r < 32; r += 8)
    tile[ty + r][tx] = src[(size_t)(t0 + ty + r) * DH + d0 + tx];
  __syncthreads();
#pragma unroll
  for (int r = 0; r < 32; r += 8)
    dst[(size_t)(d0 + ty + r) * T_SEQ + t0 + tx] = tile[tx][ty + r];
}

// ---------------- C[M,N] = A[M,K] * Bt[N,K]^T  (f16 in, fp32 out), m97 structure --------
__global__ __launch_bounds__(256) void k_gemm_lds(const f16* __restrict__ A,
                                                  const f16* __restrict__ Bt,
                                                  float* __restrict__ C,
                                                  int N, int K) {
  __shared__ __align__(16) f16 As[128 * 32];
  __shared__ __align__(16) f16 Bs[128 * 32];
  int m0 = blockIdx.y * 128, n0 = blockIdx.x * 128;
  int tid = threadIdx.x, lane = tid & 63, w = tid >> 6;
  int wm = (w >> 1) * 64, wn = (w & 1) * 64;
  int fr = lane & 15, fq = lane >> 4;
  f32x4 acc[4][4] = {};
  int r0 = tid >> 2;          // staging row (0..63)
  int c0 = (tid & 3) * 8;     // staging col in halves
  const f16* Ag0 = A + (size_t)(m0 + r0) * K + c0;
  const f16* Ag1 = A + (size_t)(m0 + 64 + r0) * K + c0;
  const f16* Bg0 = Bt + (size_t)(n0 + r0) * K + c0;
  const f16* Bg1 = Bt + (size_t)(n0 + 64 + r0) * K + c0;
  char* Asb = (char*)As;
  char* Bsb = (char*)Bs;
  for (int k0 = 0; k0 < K; k0 += 32) {
    gload16(Ag0 + k0, Asb + w * 1024);
    gload16(Ag1 + k0, Asb + 4096 + w * 1024);
    gload16(Bg0 + k0, Bsb + w * 1024);
    gload16(Bg1 + k0, Bsb + 4096 + w * 1024);
    __syncthreads();
    half8 af[4], bf[4];
#pragma unroll
    for (int i = 0; i < 4; ++i)
      af[i] = *(const half8*)(Asb + (wm + i * 16 + fr) * 64 + fq * 16);
#pragma unroll
    for (int j = 0; j < 4; ++j)
      bf[j] = *(const half8*)(Bsb + (wn + j * 16 + fr) * 64 + fq * 16);
#pragma unroll
    for (int i = 0; i < 4; ++i)
#pragma unroll
      for (int j = 0; j < 4; ++j)
        acc[i][j] = __builtin_amdgcn_mfma_f32_16x16x32_f16(af[i], bf[j], acc[i][j], 0, 0, 0);
    __syncthreads();
  }
#pragma unroll
  for (int i = 0; i < 4; ++i) {
    int row = m0 + wm + i * 16 + fq * 4;
#pragma unroll
    for (int j = 0; j < 4; ++j) {
      int col = n0 + wn + j * 16 + fr;
      float* Cp = C + (size_t)row * N + col;
#pragma unroll
      for (int rr = 0; rr < 4; ++rr) Cp[(size_t)rr * N] = acc[i][j][rr];
    }
  }
}

// ---------------- RMSNorm + RoPE + scale + pack q/k/v as f16 ----------------
__global__ __launch_bounds__(256) void k_postproc(
    const float* __restrict__ C1, const float* __restrict__ C2,
    const float* __restrict__ brk, const float* __restrict__ sscal,
    f16* __restrict__ q16, f16* __restrict__ k16, f16* __restrict__ v16) {
  int row = blockIdx.x;              // b*T + t
  int b = row >> 11, t = row & 2047;
  int lane = threadIdx.x & 63, wid = threadIdx.x >> 6;
  int ridx = lane & 31;
  float inv_freq = powf(10000.0f, -(float)(2 * ridx) / 64.0f);
  float fr = (float)t * inv_freq;
  float cs = cosf(fr), sn = sinf(fr);
  float logpos = logf(fminf((float)(t + 1), 1024.0f));
  // 1/sqrt(128) * log2(e): attention works in exp2 domain
  const float rsqrt_d_log2e = 0.08838834764831845f * 1.4426950408889634f;
#pragma unroll
  for (int p = 0; p < 5; ++p) {
    int h = p * 4 + wid; // 0..19
    float v0 = C1[(size_t)row * NQKV + h * 128 + lane];
    float v1 = C1[(size_t)row * NQKV + h * 128 + 64 + lane];
    float ss = v0 * v0 + v1 * v1;
#pragma unroll
    for (int m = 1; m < 64; m <<= 1) ss += __shfl_xor(ss, m);
    float rms = rsqrtf(ss * (1.0f / 128.0f) + 1e-6f);
    v0 *= rms; v1 *= rms;
    if (h < NH) {
      float part = __shfl_xor(v1, 32);
      float vr = (lane < 32) ? (v1 * cs + part * sn) : (v1 * cs - part * sn);
      float scale = sscal[h] * logpos * rsqrt_d_log2e;
      size_t qb = ((size_t)(b * NH + h) * T_SEQ + t) * DH;
      q16[qb + lane]      = (f16)(v0 * scale);
      q16[qb + 64 + lane] = (f16)(vr * scale);
    } else {
      int hk = h - NH;
      size_t kb = ((size_t)(b * NKV + hk) * T_SEQ + t) * DH;
      k16[kb + lane]      = (f16)v0;  // tied kv
      v16[kb + lane]      = (f16)v0;  // tied kv
      v16[kb + 64 + lane] = (f16)v1;  // v
    }
  }
  if (wid == 0) {
    float kr = C2[(size_t)row * 128 + lane] + brk[lane];
    float part = __shfl_xor(kr, 32);
    float vr = (lane < 32) ? (kr * cs + part * sn) : (kr * cs - part * sn);
    f16 hv = (f16)vr;
#pragma unroll
    for (int hk = 0; hk < NKV; ++hk)
      k16[((size_t)(b * NKV + hk) * T_SEQ + t) * DH + 64 + lane] = hv;
  }
}

// ---------------- sliding-window flash attention + silu(g) epilogue ----------------
// K tile: [64][128] f16, 256B rows, 16 slots of 16B, slot ^= (row&7)
// V^T tile: [128][64] f16, 128B rows, 8 slots,  slot ^= (row&7)
// P tile (per wave): [16][64] f16, 128B rows, 8 slots, slot ^= (row&7)
__global__ __launch_bounds__(256, 4) void k_attn(
    const f16* __restrict__ q16, const f16* __restrict__ k16, const f16* __restrict__ vt16,
    const float* __restrict__ g, float* __restrict__ out) {
  __shared__ __align__(16) f16 Ks[64 * DH];
  __shared__ __align__(16) f16 Vs[DH * 64];
  __shared__ __align__(16) f16 Ps[4 * 16 * 64];
  int bx = blockIdx.x;
  int qt = (bx & 1) ? (31 - (bx >> 1)) : (bx >> 1);  // load-balance heavy/light tiles
  int h = blockIdx.y, b = blockIdx.z;
  int hk = h >> 2;
  int tid = threadIdx.x, lane = tid & 63, w = tid >> 6;
  int i0 = qt * 64, iw = i0 + w * 16;
  int fr = lane & 15, fq = lane >> 4;

  char* Ksb = (char*)Ks;
  char* Vsb = (char*)Vs;
  char* Psb = (char*)Ps + w * 2048;

  const f16* qbase = q16 + ((size_t)(b * NH + h) * T_SEQ + iw + fr) * DH;
  half8 qf[4];
#pragma unroll
  for (int kb = 0; kb < 4; ++kb) qf[kb] = *(const half8*)&qbase[kb * 32 + fq * 8];

  f32x4 o[8] = {};
  float mrow[4] = {-1e30f, -1e30f, -1e30f, -1e30f};
  float lrow[4] = {0.f, 0.f, 0.f, 0.f};

  const f16* kg = k16 + (size_t)(b * NKV + hk) * T_SEQ * DH;   // [T][128]
  const f16* vg = vt16 + (size_t)(b * NKV + hk) * T_SEQ * DH;  // [128][T]

  int krow = tid >> 4;   // K stage: row within 16-row chunk
  int kslot = tid & 15;
  int vrow = tid >> 3;   // V stage: row within 32-row chunk
  int vslot = tid & 7;

  int jt0 = qt >= 16 ? qt - 16 : 0;
  for (int jt = jt0; jt <= qt; ++jt) {
    int j0 = jt * 64;
    // ---- stage K (16KB) + V^T (16KB) via global_load_lds, inverse-swizzled source ----
#pragma unroll
    for (int i = 0; i < 4; ++i) {
      int r = i * 16 + krow;
      int c = kslot ^ (r & 7);
      gload16(kg + (size_t)(j0 + r) * DH + c * 8, Ksb + i * 4096 + w * 1024);
    }
#pragma unroll
    for (int i = 0; i < 4; ++i) {
      int r = i * 32 + vrow;
      int c = vslot ^ (r & 7);
      gload16(vg + (size_t)r * T_SEQ + j0 + c * 8, Vsb + i * 4096 + w * 1024);
    }
    __syncthreads();   // drains vmcnt(0): tiles resident

    // ---- S = Q K^T (16 q-rows x 64 keys per wave) ----
    f32x4 s[4] = {};
#pragma unroll
    for (int nf = 0; nf < 4; ++nf) {
      int row = nf * 16 + fr;
      int sw = fr & 7;
#pragma unroll
      for (int kb = 0; kb < 4; ++kb) {
        half8 bfv = *(const half8*)(Ksb + row * 256 + ((((kb << 2) | fq) ^ sw) << 4));
        s[nf] = __builtin_amdgcn_mfma_f32_16x16x32_f16(qf[kb], bfv, s[nf], 0, 0, 0);
      }
    }
    // ---- masking: only diagonal and window-edge tiles ----
    int iol = (w << 4) + (fq << 2);
    if (jt == qt) {
#pragma unroll
      for (int nf = 0; nf < 4; ++nf) {
        int jo = nf * 16 + fr;
#pragma unroll
        for (int r = 0; r < 4; ++r)
          if (jo > iol + r) s[nf][r] = -1e30f;
      }
    } else if (qt >= 16 && jt == jt0) {
#pragma unroll
      for (int nf = 0; nf < 4; ++nf) {
        int jo = nf * 16 + fr;
#pragma unroll
        for (int r = 0; r < 4; ++r)
          if (jo < iol + r) s[nf][r] = -1e30f;
      }
    }
    // ---- online softmax (exp2 domain; log2e folded into q) ----
    float tm[4], scl[4], ls[4];
#pragma unroll
    for (int r = 0; r < 4; ++r)
      tm[r] = fmaxf(fmaxf(s[0][r], s[1][r]), fmaxf(s[2][r], s[3][r]));
#pragma unroll
    for (int r = 0; r < 4; ++r) {
      tm[r] = fmaxf(tm[r], __shfl_xor(tm[r], 1));
      tm[r] = fmaxf(tm[r], __shfl_xor(tm[r], 2));
      tm[r] = fmaxf(tm[r], __shfl_xor(tm[r], 4));
      tm[r] = fmaxf(tm[r], __shfl_xor(tm[r], 8));
      float mn = fmaxf(mrow[r], tm[r]);
      scl[r] = exp2f(mrow[r] - mn);
      mrow[r] = mn;
      ls[r] = 0.f;
    }
#pragma unroll
    for (int nf = 0; nf < 4; ++nf)
#pragma unroll
      for (int r = 0; r < 4; ++r) {
        float pv = exp2f(s[nf][r] - mrow[r]);
        s[nf][r] = pv;
        ls[r] += pv;
      }
#pragma unroll
    for (int r = 0; r < 4; ++r) {
      float t2 = ls[r];
      t2 += __shfl_xor(t2, 1); t2 += __shfl_xor(t2, 2);
      t2 += __shfl_xor(t2, 4); t2 += __shfl_xor(t2, 8);
      lrow[r] = lrow[r] * scl[r] + t2;
#pragma unroll
      for (int of = 0; of < 8; ++of) o[of][r] *= scl[r];
    }
    // ---- P -> per-wave LDS (swizzled), wave-local ordering only ----
#pragma unroll
    for (int nf = 0; nf < 4; ++nf) {
      int sbase = (nf << 1) + (fr >> 3);
      int boff = (fr & 7) << 1;
#pragma unroll
      for (int r = 0; r < 4; ++r) {
        int q = (fq << 2) + r;
        *(f16*)(Psb + q * 128 + ((sbase ^ (q & 7)) << 4) + boff) = (f16)s[nf][r];
      }
    }
    asm volatile("s_waitcnt lgkmcnt(0)" ::: "memory");
    __builtin_amdgcn_sched_barrier(0);
    half8 pf0 = *(const half8*)(Psb + fr * 128 + (((fq) ^ (fr & 7)) << 4));
    half8 pf1 = *(const half8*)(Psb + fr * 128 + (((4 | fq) ^ (fr & 7)) << 4));
    // ---- O += P V ----
#pragma unroll
    for (int of = 0; of < 8; ++of) {
      int vrow0 = of * 16 + fr;
      int sw = fr & 7;
      half8 v0 = *(const half8*)(Vsb + vrow0 * 128 + ((fq ^ sw) << 4));
      half8 v1 = *(const half8*)(Vsb + vrow0 * 128 + (((4 | fq) ^ sw) << 4));
      o[of] = __builtin_amdgcn_mfma_f32_16x16x32_f16(pf0, v0, o[of], 0, 0, 0);
      o[of] = __builtin_amdgcn_mfma_f32_16x16x32_f16(pf1, v1, o[of], 0, 0, 0);
    }
    __syncthreads();   // all waves done reading Ks/Vs before next stage
  }
  // ---- epilogue: normalize + silu(g), write (B,T,H,D) ----
  const float* gb = g + ((size_t)(b * T_SEQ) + iw) * DM + h * DH;
  float* ob = out + ((size_t)(b * T_SEQ) + iw) * DM + h * DH;
#pragma unroll
  for (int r = 0; r < 4; ++r) {
    float inv = 1.0f / lrow[r];
    int ir = fq * 4 + r;
#pragma unroll
    for (int of = 0; of < 8; ++of) {
      int d = of * 16 + fr;
      float gv = gb[(size_t)ir * DM + d];
      float sig = gv / (1.0f + expf(-gv));
      ob[(size_t)ir * DM + d] = o[of][r] * inv * sig;
    }
  }
}

extern "C" void kernel_launch(void* const* d_in, const int* in_sizes, int n_in,
                              void* d_out, int out_size, void* d_ws, size_t ws_size,
                              hipStream_t stream) {
  const float* x     = (const float*)d_in[0];
  const float* Wqkv  = (const float*)d_in[1];
  const float* Wrk   = (const float*)d_in[2];
  const float* brk   = (const float*)d_in[3];
  const float* sscal = (const float*)d_in[4];
  const float* Wg    = (const float*)d_in[5];
  float* out = (float*)d_out;
  char* ws = (char*)d_ws;
  size_t off = 0;
  auto alloc = [&](size_t bytes) -> void* {
    void* p = ws + off;
    off += (bytes + 255) & ~(size_t)255;
    return p;
  };
  f16* x16     = (f16*)alloc((size_t)M_ROWS * DM * 2);
  f16* WqkvT   = (f16*)alloc((size_t)NQKV * DM * 2);
  f16* WrkT    = (f16*)alloc((size_t)128 * DM * 2);   // 64 real rows, padded to 128
  f16* WgT     = (f16*)alloc((size_t)DM * DM * 2);
  float* C1    = (float*)alloc((size_t)M_ROWS * NQKV * 4);
  float* C2    = (float*)alloc((size_t)M_ROWS * 128 * 4);
  float* C3    = (float*)alloc((size_t)M_ROWS * DM * 4);
  f16* q16     = (f16*)alloc((size_t)B_SZ * NH * T_SEQ * DH * 2);
  f16* k16     = (f16*)alloc((size_t)B_SZ * NKV * T_SEQ * DH * 2);
  f16* v16     = (f16*)alloc((size_t)B_SZ * NKV * T_SEQ * DH * 2);
  f16* vt16    = (f16*)alloc((size_t)B_SZ * NKV * T_SEQ * DH * 2);

  k_cvt<<<(M_ROWS * DM / 4 + 255) / 256, 256, 0, stream>>>(x, x16, M_ROWS * DM);
  k_cvt_t<<<dim3(DM / 32, NQKV / 32), 256, 0, stream>>>(Wqkv, WqkvT, DM, NQKV);
  k_cvt_t<<<dim3(DM / 32, 64 / 32), 256, 0, stream>>>(Wrk, WrkT, DM, 64);
  k_cvt_t<<<dim3(DM / 32, DM / 32), 256, 0, stream>>>(Wg, WgT, DM, DM);

  k_gemm_lds<<<dim3(NQKV / 128, M_ROWS / 128), 256, 0, stream>>>(x16, WqkvT, C1, NQKV, DM);
  k_gemm_lds<<<dim3(1, M_ROWS / 128), 256, 0, stream>>>(x16, WrkT, C2, 128, DM);
  k_gemm_lds<<<dim3(DM / 128, M_ROWS / 128), 256, 0, stream>>>(x16, WgT, C3, DM, DM);

  k_postproc<<<M_ROWS, 256, 0, stream>>>(C1, C2, brk, sscal, q16, k16, v16);
  k_vt<<<dim3(T_SEQ / 32, DH / 32, B_SZ * NKV), 256, 0, stream>>>(v16, vt16);

  k_attn<<<dim3(T_SEQ / 64, NH, B_SZ), 256, 0, stream>>>(q16, k16, vt16, C3, out);
}